// Round 2
// baseline (670.848 us; speedup 1.0000x reference)
//
#include <hip/hip_runtime.h>
#include <math.h>

#define NB1 2048          // blocks in pass 1 (8 per CU)
#define TPB 256           // threads per block
#define WAVES_PER_BLOCK (TPB / 64)
#define GROUPS_PER_WAVE 16                      // 4 lanes per row-group
#define TOTAL_GROUPS (NB1 * WAVES_PER_BLOCK * GROUPS_PER_WAVE)   // 131072
#define NLEAD (TPB / 4)                         // leaders per block = 64
#define NBCAND (NLEAD * 5)                      // 320 block-local candidates
#define NCAND (NB1 * 5)                         // 10240 global candidates

constexpr float EPS = 1e-6f;

typedef float f32x4 __attribute__((ext_vector_type(4)));

__device__ __forceinline__ bool better(float v, int i, float bv, int bi) {
    // strictly-greater wins; on exact tie, lower row index wins (jax top_k order)
    return (v > bv) || (v == bv && i < bi);
}

// pass-1 insert: rows arrive in increasing index order per group, so a value
// equal to tv[4] has a larger index and correctly loses -> cheap reject exact
__device__ __forceinline__ void insert5_asc(float nv, int ni, float tv[5], int ti[5]) {
    if (nv > tv[4]) {
        #pragma unroll
        for (int j = 0; j < 5; j++) {           // bubble-insert, keeps sorted desc
            bool b = better(nv, ni, tv[j], ti[j]);
            float ov = tv[j]; int oi = ti[j];
            if (b) { tv[j] = nv; ti[j] = ni; nv = ov; ni = oi; }
        }
    }
}

// order-agnostic insert (final pass: candidates arrive in arbitrary index order)
__device__ __forceinline__ void insert5_any(float nv, int ni, float tv[5], int ti[5]) {
    if (better(nv, ni, tv[4], ti[4])) {
        #pragma unroll
        for (int j = 0; j < 5; j++) {
            bool b = better(nv, ni, tv[j], ti[j]);
            float ov = tv[j]; int oi = ti[j];
            if (b) { tv[j] = nv; ti[j] = ni; nv = ov; ni = oi; }
        }
    }
}

__global__ __launch_bounds__(TPB) void sim_block_topk(
    const float* __restrict__ W, const int* __restrict__ qidx,
    int V, float* __restrict__ bv, int* __restrict__ bi)
{
    const int tid  = threadIdx.x;
    const int lane = tid & 63;
    const int sub  = lane & 3;                  // chunk id within 4-lane group
    const int grp  = lane >> 2;                 // group within wave, 0..15
    const int wave = tid >> 6;
    const int groupGlobal =
        (blockIdx.x * WAVES_PER_BLOCK + wave) * GROUPS_PER_WAVE + grp;

    const int q = qidx[0];

    // q fragment: lane covers elements {sub*4 + j*16 .. +3} for j=0..7 (32 floats)
    f32x4 qv[8];
    const f32x4* Q4 = (const f32x4*)(W + (size_t)q * 128);
    #pragma unroll
    for (int j = 0; j < 8; j++) qv[j] = Q4[sub + 4 * j];

    float qn2 = 0.f;
    #pragma unroll
    for (int j = 0; j < 8; j++)
        qn2 += qv[j][0]*qv[j][0] + qv[j][1]*qv[j][1] + qv[j][2]*qv[j][2] + qv[j][3]*qv[j][3];
    qn2 += __shfl_xor(qn2, 1);
    qn2 += __shfl_xor(qn2, 2);
    const float qn = sqrtf(qn2);

    // per-lane register top-5 (redundant across the 4 lanes of a group ->
    // uniform control flow in the hot loop; leader writes at the end)
    float tv[5]; int ti[5];
    #pragma unroll
    for (int j = 0; j < 5; j++) { tv[j] = -INFINITY; ti[j] = 0x7fffffff; }

    // pairs of consecutive rows per group; NONTEMPORAL loads: W is streamed
    // exactly once, bypass L2 allocation (the 6.5 TB/s fill kernels use nt).
    // V is even and base is even, so base < V implies base+1 < V.
    for (int base = groupGlobal * 2; base < V; base += 2 * TOTAL_GROUPS) {
        const f32x4* Wr = (const f32x4*)(W + (size_t)base * 128);
        f32x4 a[8], b[8];
        #pragma unroll
        for (int j = 0; j < 8; j++) a[j] = __builtin_nontemporal_load(Wr + sub + 4 * j);
        #pragma unroll
        for (int j = 0; j < 8; j++) b[j] = __builtin_nontemporal_load(Wr + 32 + sub + 4 * j);

        // per-row arithmetic identical (bitwise) to verified kernel version
        float dot0 = 0.f, nr0 = 0.f, dot1 = 0.f, nr1 = 0.f;
        #pragma unroll
        for (int j = 0; j < 8; j++) {
            dot0 += a[j][0]*qv[j][0] + a[j][1]*qv[j][1] + a[j][2]*qv[j][2] + a[j][3]*qv[j][3];
            nr0  += a[j][0]*a[j][0]  + a[j][1]*a[j][1]  + a[j][2]*a[j][2]  + a[j][3]*a[j][3];
        }
        #pragma unroll
        for (int j = 0; j < 8; j++) {
            dot1 += b[j][0]*qv[j][0] + b[j][1]*qv[j][1] + b[j][2]*qv[j][2] + b[j][3]*qv[j][3];
            nr1  += b[j][0]*b[j][0]  + b[j][1]*b[j][1]  + b[j][2]*b[j][2]  + b[j][3]*b[j][3];
        }
        // 2 shfl stages per quantity (4-lane group) -> all 4 lanes hold sums
        dot0 += __shfl_xor(dot0, 1); dot0 += __shfl_xor(dot0, 2);
        nr0  += __shfl_xor(nr0,  1); nr0  += __shfl_xor(nr0,  2);
        dot1 += __shfl_xor(dot1, 1); dot1 += __shfl_xor(dot1, 2);
        nr1  += __shfl_xor(nr1,  1); nr1  += __shfl_xor(nr1,  2);

        float sim0 = dot0 / fmaxf(qn * sqrtf(nr0), EPS);
        float sim1 = dot1 / fmaxf(qn * sqrtf(nr1), EPS);
        insert5_asc(sim0, base,     tv, ti);
        insert5_asc(sim1, base + 1, tv, ti);
    }

    // ---- block combine: 64 leaders x 5 -> block top-5 (parallel argmax) ----
    __shared__ float s_v[NBCAND];
    __shared__ int   s_i[NBCAND];
    __shared__ float sw_v[WAVES_PER_BLOCK];
    __shared__ int   sw_i[WAVES_PER_BLOCK], sw_p[WAVES_PER_BLOCK];

    if (sub == 0) {
        const int leader = tid >> 2;
        #pragma unroll
        for (int j = 0; j < 5; j++) { s_v[leader*5 + j] = tv[j]; s_i[leader*5 + j] = ti[j]; }
    }
    __syncthreads();

    for (int k = 0; k < 5; k++) {
        float v = -INFINITY; int i = 0x7fffffff; int p = 0;
        for (int e = tid; e < NBCAND; e += TPB) {
            if (better(s_v[e], s_i[e], v, i)) { v = s_v[e]; i = s_i[e]; p = e; }
        }
        #pragma unroll
        for (int m = 32; m >= 1; m >>= 1) {
            float ov = __shfl_xor(v, m);
            int   oi = __shfl_xor(i, m);
            int   op = __shfl_xor(p, m);
            if (better(ov, oi, v, i)) { v = ov; i = oi; p = op; }
        }
        if (lane == 0) { sw_v[wave] = v; sw_i[wave] = i; sw_p[wave] = p; }
        __syncthreads();
        if (tid == 0) {
            for (int w = 1; w < WAVES_PER_BLOCK; w++)
                if (better(sw_v[w], sw_i[w], sw_v[0], sw_i[0])) {
                    sw_v[0] = sw_v[w]; sw_i[0] = sw_i[w]; sw_p[0] = sw_p[w];
                }
            bv[blockIdx.x*5 + k] = sw_v[0];
            bi[blockIdx.x*5 + k] = sw_i[0];
            s_v[sw_p[0]] = -INFINITY;
        }
        __syncthreads();
    }
}

__global__ __launch_bounds__(256) void final_topk(
    const float* __restrict__ bv, const int* __restrict__ bi,
    float* __restrict__ out)
{
    // NCAND=10240 won't fit a staged-LDS scan; per-thread register top-5
    // first (40 candidates/thread), then 5-round argmax over 256x5 in LDS.
    __shared__ float s_v[TPB * 5];
    __shared__ int   s_i[TPB * 5];
    __shared__ float sw_v[4];
    __shared__ int   sw_i[4], sw_p[4];

    const int tid  = threadIdx.x;
    const int lane = tid & 63;

    float tv[5]; int ti[5];
    #pragma unroll
    for (int j = 0; j < 5; j++) { tv[j] = -INFINITY; ti[j] = 0x7fffffff; }

    for (int e = tid; e < NCAND; e += TPB)
        insert5_any(bv[e], bi[e], tv, ti);

    #pragma unroll
    for (int j = 0; j < 5; j++) { s_v[tid*5 + j] = tv[j]; s_i[tid*5 + j] = ti[j]; }
    __syncthreads();

    for (int k = 0; k < 5; k++) {
        float v = -INFINITY; int i = 0x7fffffff; int p = 0;
        for (int e = tid; e < TPB * 5; e += TPB) {
            if (better(s_v[e], s_i[e], v, i)) { v = s_v[e]; i = s_i[e]; p = e; }
        }
        #pragma unroll
        for (int m = 32; m >= 1; m >>= 1) {
            float ov = __shfl_xor(v, m);
            int   oi = __shfl_xor(i, m);
            int   op = __shfl_xor(p, m);
            if (better(ov, oi, v, i)) { v = ov; i = oi; p = op; }
        }
        if (lane == 0) { int w = tid >> 6; sw_v[w] = v; sw_i[w] = i; sw_p[w] = p; }
        __syncthreads();
        if (tid == 0) {
            for (int w = 1; w < 4; w++)
                if (better(sw_v[w], sw_i[w], sw_v[0], sw_i[0])) {
                    sw_v[0] = sw_v[w]; sw_i[0] = sw_i[w]; sw_p[0] = sw_p[w];
                }
            out[k]     = sw_v[0];
            out[5 + k] = (float)sw_i[0];
            s_v[sw_p[0]] = -INFINITY;
        }
        __syncthreads();
    }
}

extern "C" void kernel_launch(void* const* d_in, const int* in_sizes, int n_in,
                              void* d_out, int out_size, void* d_ws, size_t ws_size,
                              hipStream_t stream) {
    const float* W    = (const float*)d_in[0];
    const int*   qidx = (const int*)d_in[1];   // low word of int64 is correct (LE, V < 2^31)
    const int V = in_sizes[0] / 128;

    float* bv = (float*)d_ws;
    int*   bi = (int*)((char*)d_ws + (size_t)NB1 * 5 * sizeof(float));

    sim_block_topk<<<NB1, TPB, 0, stream>>>(W, qidx, V, bv, bi);
    final_topk<<<1, 256, 0, stream>>>(bv, bi, (float*)d_out);
}

// Round 3
// 641.942 us; speedup vs baseline: 1.0450x; 1.0450x over previous
//
#include <hip/hip_runtime.h>
#include <math.h>

#define NB1 1024          // blocks in pass 1
#define TPB 256           // threads per block
#define WPB (TPB / 64)                          // 4 waves per block
#define NWAVE (NB1 * WPB)                       // 4096 waves total
#define ROWS_PER_ITER 8                         // rows per wave per iteration
#define STRIDE (NWAVE * ROWS_PER_ITER)          // 32768-row grid stride
#define NLEADER (WPB * 2)                       // 8 distinct top-5 lists per block
#define NBCAND (NLEADER * 5)                    // 40 block-local candidates
#define NCAND (NB1 * 5)                         // 5120 global candidates

constexpr float EPS = 1e-6f;

typedef float f32x4 __attribute__((ext_vector_type(4)));

__device__ __forceinline__ bool better(float v, int i, float bv, int bi) {
    // strictly-greater wins; on exact tie, lower row index wins (jax top_k order)
    return (v > bv) || (v == bv && i < bi);
}

// pass-1 insert: rows arrive in increasing index order per lane, so a value
// equal to tv[4] has a larger index and correctly loses -> cheap reject exact
__device__ __forceinline__ void insert5_asc(float nv, int ni, float tv[5], int ti[5]) {
    if (nv > tv[4]) {
        #pragma unroll
        for (int j = 0; j < 5; j++) {           // bubble-insert, keeps sorted desc
            bool b = better(nv, ni, tv[j], ti[j]);
            float ov = tv[j]; int oi = ti[j];
            if (b) { tv[j] = nv; ti[j] = ni; nv = ov; ni = oi; }
        }
    }
}

// order-agnostic insert (final pass: candidates arrive in arbitrary index order)
__device__ __forceinline__ void insert5_any(float nv, int ni, float tv[5], int ti[5]) {
    if (better(nv, ni, tv[4], ti[4])) {
        #pragma unroll
        for (int j = 0; j < 5; j++) {
            bool b = better(nv, ni, tv[j], ti[j]);
            float ov = tv[j]; int oi = ti[j];
            if (b) { tv[j] = nv; ti[j] = ni; nv = ov; ni = oi; }
        }
    }
}

__global__ __launch_bounds__(TPB) void sim_block_topk(
    const float* __restrict__ W, const int* __restrict__ qidx,
    int V, float* __restrict__ bv, int* __restrict__ bi)
{
    const int tid   = threadIdx.x;
    const int lane  = tid & 63;
    const int wave  = tid >> 6;
    const int hi    = lane >> 5;                // 0: even row of pair, 1: odd row
    const int hlane = lane & 31;                // position within 32-lane half
    const int waveGlobal = blockIdx.x * WPB + wave;

    const int q = qidx[0];

    // each lane owns q floats [hlane*4, hlane*4+4): one float4, same fragment
    // for every row since in-row position is fixed by hlane
    const f32x4* Q4 = (const f32x4*)(W + (size_t)q * 128);
    const f32x4 qv = Q4[hlane];

    float qn2 = qv[0]*qv[0] + qv[1]*qv[1] + qv[2]*qv[2] + qv[3]*qv[3];
    #pragma unroll
    for (int m = 1; m <= 16; m <<= 1) qn2 += __shfl_xor(qn2, m);
    const float qn = sqrtf(qn2);

    float tv[5]; int ti[5];
    #pragma unroll
    for (int j = 0; j < 5; j++) { tv[j] = -INFINITY; ti[j] = 0x7fffffff; }

    // wave-linear loads: each dwordx4 instruction reads a CONTIGUOUS aligned
    // 1 KB (64 lanes x 16 B) = one row pair. 4 instructions = 8 rows / iter.
    // V % ROWS_PER_ITER == 0 (V = 1e6), so no tail guard is needed.
    for (int chunk = waveGlobal * ROWS_PER_ITER; chunk < V; chunk += STRIDE) {
        const f32x4* P4 = (const f32x4*)(W + (size_t)chunk * 128);
        f32x4 a[4];
        #pragma unroll
        for (int p = 0; p < 4; p++)
            a[p] = __builtin_nontemporal_load(P4 + p * 64 + lane);

        float dt[4], nr[4];
        #pragma unroll
        for (int p = 0; p < 4; p++) {
            dt[p] = a[p][0]*qv[0] + a[p][1]*qv[1] + a[p][2]*qv[2] + a[p][3]*qv[3];
            nr[p] = a[p][0]*a[p][0] + a[p][1]*a[p][1] + a[p][2]*a[p][2] + a[p][3]*a[p][3];
        }
        // 5-stage butterfly within each 32-lane half; 8 independent shuffles
        // per stage give good ILP on the LDS pipe
        #pragma unroll
        for (int m = 1; m <= 16; m <<= 1) {
            #pragma unroll
            for (int p = 0; p < 4; p++) dt[p] += __shfl_xor(dt[p], m);
            #pragma unroll
            for (int p = 0; p < 4; p++) nr[p] += __shfl_xor(nr[p], m);
        }
        #pragma unroll
        for (int p = 0; p < 4; p++) {
            float sim = dt[p] / fmaxf(qn * sqrtf(nr[p]), EPS);
            insert5_asc(sim, chunk + 2 * p + hi, tv, ti);
        }
    }

    // ---- block combine: 8 leader lists x 5 -> block top-5 ----
    __shared__ float s_v[NBCAND];
    __shared__ int   s_i[NBCAND];
    __shared__ float sw_v[WPB];
    __shared__ int   sw_i[WPB], sw_p[WPB];

    if (hlane == 0) {                           // lanes 0 and 32 of each wave
        const int leader = wave * 2 + hi;
        #pragma unroll
        for (int j = 0; j < 5; j++) { s_v[leader*5 + j] = tv[j]; s_i[leader*5 + j] = ti[j]; }
    }
    __syncthreads();

    for (int k = 0; k < 5; k++) {
        float v = -INFINITY; int i = 0x7fffffff; int p = 0;
        for (int e = tid; e < NBCAND; e += TPB) {
            if (better(s_v[e], s_i[e], v, i)) { v = s_v[e]; i = s_i[e]; p = e; }
        }
        #pragma unroll
        for (int m = 32; m >= 1; m >>= 1) {
            float ov = __shfl_xor(v, m);
            int   oi = __shfl_xor(i, m);
            int   op = __shfl_xor(p, m);
            if (better(ov, oi, v, i)) { v = ov; i = oi; p = op; }
        }
        if (lane == 0) { sw_v[wave] = v; sw_i[wave] = i; sw_p[wave] = p; }
        __syncthreads();
        if (tid == 0) {
            for (int w = 1; w < WPB; w++)
                if (better(sw_v[w], sw_i[w], sw_v[0], sw_i[0])) {
                    sw_v[0] = sw_v[w]; sw_i[0] = sw_i[w]; sw_p[0] = sw_p[w];
                }
            bv[blockIdx.x*5 + k] = sw_v[0];
            bi[blockIdx.x*5 + k] = sw_i[0];
            s_v[sw_p[0]] = -INFINITY;
        }
        __syncthreads();
    }
}

__global__ __launch_bounds__(256) void final_topk(
    const float* __restrict__ bv, const int* __restrict__ bi,
    float* __restrict__ out)
{
    // per-thread register top-5 over 20 candidates, then 5-round argmax
    __shared__ float s_v[256 * 5];
    __shared__ int   s_i[256 * 5];
    __shared__ float sw_v[4];
    __shared__ int   sw_i[4], sw_p[4];

    const int tid  = threadIdx.x;
    const int lane = tid & 63;

    float tv[5]; int ti[5];
    #pragma unroll
    for (int j = 0; j < 5; j++) { tv[j] = -INFINITY; ti[j] = 0x7fffffff; }

    for (int e = tid; e < NCAND; e += 256)
        insert5_any(bv[e], bi[e], tv, ti);

    #pragma unroll
    for (int j = 0; j < 5; j++) { s_v[tid*5 + j] = tv[j]; s_i[tid*5 + j] = ti[j]; }
    __syncthreads();

    for (int k = 0; k < 5; k++) {
        float v = -INFINITY; int i = 0x7fffffff; int p = 0;
        for (int e = tid; e < 256 * 5; e += 256) {
            if (better(s_v[e], s_i[e], v, i)) { v = s_v[e]; i = s_i[e]; p = e; }
        }
        #pragma unroll
        for (int m = 32; m >= 1; m >>= 1) {
            float ov = __shfl_xor(v, m);
            int   oi = __shfl_xor(i, m);
            int   op = __shfl_xor(p, m);
            if (better(ov, oi, v, i)) { v = ov; i = oi; p = op; }
        }
        if (lane == 0) { int w = tid >> 6; sw_v[w] = v; sw_i[w] = i; sw_p[w] = p; }
        __syncthreads();
        if (tid == 0) {
            for (int w = 1; w < 4; w++)
                if (better(sw_v[w], sw_i[w], sw_v[0], sw_i[0])) {
                    sw_v[0] = sw_v[w]; sw_i[0] = sw_i[w]; sw_p[0] = sw_p[w];
                }
            out[k]     = sw_v[0];
            out[5 + k] = (float)sw_i[0];
            s_v[sw_p[0]] = -INFINITY;
        }
        __syncthreads();
    }
}

extern "C" void kernel_launch(void* const* d_in, const int* in_sizes, int n_in,
                              void* d_out, int out_size, void* d_ws, size_t ws_size,
                              hipStream_t stream) {
    const float* W    = (const float*)d_in[0];
    const int*   qidx = (const int*)d_in[1];   // low word of int64 is correct (LE, V < 2^31)
    const int V = in_sizes[0] / 128;

    float* bv = (float*)d_ws;
    int*   bi = (int*)((char*)d_ws + (size_t)NB1 * 5 * sizeof(float));

    sim_block_topk<<<NB1, TPB, 0, stream>>>(W, qidx, V, bv, bi);
    final_topk<<<1, 256, 0, stream>>>(bv, bi, (float*)d_out);
}